// Round 1
// baseline (454.312 us; speedup 1.0000x reference)
//
#include <hip/hip_runtime.h>
#include <math.h>

#define N_    64
#define C_IN_ 64
#define T_    64
#define V_    25
#define TV_   1600   // T_*V_

__device__ __forceinline__ float tanh_fast(float x) {
    x = fminf(15.f, fmaxf(-15.f, x));
    float e = __expf(2.f * x);
    return __fdividef(e - 1.f, e + 1.f);
}

__device__ __forceinline__ void block_reduce_atomic(float val, float* target, float* redbuf, int tid) {
    #pragma unroll
    for (int off = 32; off > 0; off >>= 1) val += __shfl_down(val, off, 64);
    int wid = tid >> 6, lane = tid & 63;
    if (lane == 0) redbuf[wid] = val;
    __syncthreads();
    if (tid == 0) atomicAdd(target, redbuf[0] + redbuf[1] + redbuf[2] + redbuf[3]);
    __syncthreads();
}

// ---------------------------------------------------------------------------
// K1: per (n,v) block: data_bn, +pe, qkv projections, 8-head attention,
//     attn_w projection. Writes ao_out[n][o][t][v] (o in 0..15).
// ---------------------------------------------------------------------------
__global__ __launch_bounds__(256) void attn_kernel(
    const float* __restrict__ x, const float* __restrict__ pe,
    const float* __restrict__ dbg, const float* __restrict__ dbb,
    const float* __restrict__ qkv_w, const float* __restrict__ qkv_b,
    const float* __restrict__ attn_w, const float* __restrict__ attn_b,
    float* __restrict__ ao_out)
{
    // phase1: xn[4096] @0, yb[4096] @4096
    // phase2 overlays: weights(64x65=4160) @0, ao2(16x64) @4416, mu(16) @5440
    // persistent: fq@8192 fk@9216 fv@10240 pq@11264 pk@12288 (each 16x64)
    __shared__ float sm[13312];
    float* xn = sm;
    float* yb = sm + 4096;
    float* fq = sm + 8192;
    float* fk = sm + 9216;
    float* fv = sm + 10240;
    float* pq = sm + 11264;
    float* pk = sm + 12288;
    float* weights = sm;          // stride 65 (bank-conflict pad)
    float* ao2 = sm + 4416;
    float* mu  = sm + 5440;

    const int b = blockIdx.x;
    const int n = b / V_, v = b % V_;
    const int tid = threadIdx.x;
    const float rs = rsqrtf(1.f + 1e-5f);

    // load + data_bn + pe
    for (int i = tid; i < 4096; i += 256) {
        int c = i >> 6, t = i & 63;
        float xv = x[((n * 64 + c) * 64 + t) * 25 + v];
        xn[i] = xv * (dbg[c * 25 + v] * rs) + dbb[c * 25 + v];
        yb[i] = xv + pe[(c * 64 + t) * 25 + v];
    }
    __syncthreads();

    // qkv: 80 output rows x 64 t.  rows: 0-15 fq, 16-31 fk, 32-47 fv, 48-63 pq, 64-79 pk
    for (int task = tid; task < 5120; task += 256) {
        int r = task >> 6, t = task & 63;
        const float* src; int wrow; float* dst; bool isq = false;
        if (r < 16)      { src = xn; wrow = r;      dst = fq + r * 64;        isq = true; }
        else if (r < 32) { src = xn; wrow = r;      dst = fk + (r - 16) * 64; }
        else if (r < 48) { src = xn; wrow = r + 16; dst = fv + (r - 32) * 64; }
        else if (r < 64) { src = yb; wrow = r - 48; dst = pq + (r - 48) * 64; isq = true; }
        else             { src = yb; wrow = r - 48; dst = pk + (r - 64) * 64; }
        const float* wr = qkv_w + wrow * 64;
        float acc = 0.f;
        #pragma unroll
        for (int c = 0; c < 64; ++c) acc += wr[c] * src[c * 64 + t];
        acc += qkv_b[wrow];
        if (isq) acc *= 0.70710678118654752f;  // DKH^-0.5
        dst[t] = acc;
    }
    __syncthreads();

    // mu = mean_t fq  (per q channel)
    if (tid < 16) {
        float s = 0.f;
        #pragma unroll
        for (int t = 0; t < 64; ++t) s += fq[tid * 64 + t];
        mu[tid] = s * (1.f / 64.f);
    }
    __syncthreads();

    // per-head: weights = tanh(pairwise+logits) + tanh(unary+logits); ao = W @ fv^T
    for (int h = 0; h < 8; ++h) {
        int c0 = 2 * h, c1 = 2 * h + 1;
        float mu0 = mu[c0], mu1 = mu[c1];
        for (int i = tid; i < 4096; i += 256) {
            int s = i >> 6, t = i & 63;
            float pk0 = pk[c0 * 64 + t], pk1 = pk[c1 * 64 + t];
            float fk0 = fk[c0 * 64 + t], fk1 = fk[c1 * 64 + t];
            float lp = pq[c0 * 64 + s] * pk0 + pq[c1 * 64 + s] * pk1;
            float pw = (fq[c0 * 64 + s] - mu0) * fk0 + (fq[c1 * 64 + s] - mu1) * fk1;
            float un = mu0 * fk0 + mu1 * fk1;
            weights[s * 65 + t] = tanh_fast(pw + lp) + tanh_fast(un + lp);
        }
        __syncthreads();
        if (tid < 128) {
            int c = tid >> 6, s = tid & 63;
            const float* fvr = fv + (c0 + c) * 64;
            float acc = 0.f;
            #pragma unroll
            for (int t = 0; t < 64; ++t) acc += weights[s * 65 + t] * fvr[t];
            ao2[(c0 + c) * 64 + s] = acc;
        }
        __syncthreads();
    }

    // attn_w projection: ao_final[o][t] = attn_b[o] + sum_c attn_w[o][c]*ao2[c][t]
    for (int i = tid; i < 1024; i += 256) {
        int o = i >> 6, t = i & 63;
        float acc = attn_b[o];
        #pragma unroll
        for (int c = 0; c < 16; ++c) acc += attn_w[o * 16 + c] * ao2[c * 64 + t];
        ao_out[((n * 16 + o) * 64 + t) * 25 + v] = acc;
    }
}

// ---------------------------------------------------------------------------
// K2: tcn conv (ocg 0..7 -> 6 oc each) or ao+residual (ocg==8 -> ch 48..63).
//     Writes pre-BN result into out, accumulates per-(n,c) sums into se.
// ---------------------------------------------------------------------------
__global__ __launch_bounds__(256) void tcn_kernel(
    const float* __restrict__ x, const float* __restrict__ tcn_w,
    const float* __restrict__ tcn_b, const float* __restrict__ tg,
    const float* __restrict__ tb, const float* __restrict__ ao_ws,
    float* __restrict__ out, float* __restrict__ se)
{
    const int ocg = blockIdx.x;   // 0..8
    const int n = blockIdx.y;
    const int tid = threadIdx.x;
    const float rs = rsqrtf(1.f + 1e-5f);
    __shared__ float redbuf[4];

    if (ocg == 8) {
        float chsum[16];
        #pragma unroll
        for (int c = 0; c < 16; ++c) chsum[c] = 0.f;
        for (int pos = tid; pos < TV_; pos += 256) {
            #pragma unroll
            for (int c = 0; c < 16; ++c) {
                float val = ao_ws[(n * 16 + c) * TV_ + pos] + x[(n * 64 + 48 + c) * TV_ + pos];
                out[(n * 64 + 48 + c) * TV_ + pos] = val;
                chsum[c] += val;
            }
        }
        #pragma unroll
        for (int c = 0; c < 16; ++c)
            block_reduce_atomic(chsum[c], &se[n * 64 + 48 + c], redbuf, tid);
    } else {
        __shared__ float wsm[64 * 54];   // [ci][kt][j]
        for (int i = tid; i < 64 * 54; i += 256) {
            int ci = i / 54, r = i - ci * 54;
            int kt = r / 6, j = r - kt * 6;
            wsm[i] = tcn_w[((ocg * 6 + j) * 64 + ci) * 9 + kt];
        }
        __syncthreads();

        float a_s[6], c_s[6];
        #pragma unroll
        for (int j = 0; j < 6; ++j) {
            int oc = ocg * 6 + j;
            a_s[j] = tg[oc] * rs;
            c_s[j] = tcn_b[oc] * a_s[j] + tb[oc];
        }

        int tc[7], vc[7];
        #pragma unroll
        for (int k = 0; k < 7; ++k) {
            int pos = tid + k * 256;
            tc[k] = pos / 25;
            vc[k] = pos - tc[k] * 25;
        }

        float acc[7][6] = {};
        for (int ci = 0; ci < 64; ++ci) {
            const float* xp = x + (n * 64 + ci) * TV_;
            #pragma unroll
            for (int kt = 0; kt < 9; ++kt) {
                float w6[6];
                #pragma unroll
                for (int j = 0; j < 6; ++j) w6[j] = wsm[ci * 54 + kt * 6 + j];
                #pragma unroll
                for (int k = 0; k < 7; ++k) {
                    int tt = tc[k] + kt - 4;
                    float xv = (tt >= 0 && tt < 64) ? xp[tt * 25 + vc[k]] : 0.f;
                    #pragma unroll
                    for (int j = 0; j < 6; ++j) acc[k][j] += w6[j] * xv;
                }
            }
        }

        float chsum[6];
        #pragma unroll
        for (int j = 0; j < 6; ++j) chsum[j] = 0.f;
        #pragma unroll
        for (int k = 0; k < 7; ++k) {
            int pos = tid + k * 256;
            if (pos < TV_) {
                #pragma unroll
                for (int j = 0; j < 6; ++j) {
                    int c = ocg * 6 + j;
                    float val = acc[k][j] * a_s[j] + c_s[j] + x[(n * 64 + c) * TV_ + pos];
                    out[(n * 64 + c) * TV_ + pos] = val;
                    chsum[j] += val;
                }
            }
        }
        #pragma unroll
        for (int j = 0; j < 6; ++j)
            block_reduce_atomic(chsum[j], &se[n * 64 + ocg * 6 + j], redbuf, tid);
    }
}

// ---------------------------------------------------------------------------
// K3: SE gate MLP per n: gate = sigmoid(relu(se/1600 @ fc1^T + b1) @ fc2^T + b2)
// ---------------------------------------------------------------------------
__global__ __launch_bounds__(64) void gate_kernel(
    const float* __restrict__ se,
    const float* __restrict__ fc1w, const float* __restrict__ fc1b,
    const float* __restrict__ fc2w, const float* __restrict__ fc2b,
    float* __restrict__ gate)
{
    const int n = blockIdx.x;
    const int tid = threadIdx.x;   // 64
    __shared__ float seL[64], hid[32];
    seL[tid] = se[n * 64 + tid] * (1.f / (float)TV_);
    __syncthreads();
    if (tid < 32) {
        float a = fc1b[tid];
        #pragma unroll
        for (int c = 0; c < 64; ++c) a += fc1w[tid * 64 + c] * seL[c];
        hid[tid] = fmaxf(a, 0.f);
    }
    __syncthreads();
    float g = fc2b[tid];
    #pragma unroll
    for (int j = 0; j < 32; ++j) g += fc2w[tid * 32 + j] * hid[j];
    gate[n * 64 + tid] = 1.f / (1.f + __expf(-g));
}

// ---------------------------------------------------------------------------
// K4: out = relu((result*(1+gate)) * bn_s + bn_b), float4 over 1,638,400 vecs
// ---------------------------------------------------------------------------
__global__ __launch_bounds__(256) void final_kernel(
    float* __restrict__ out, const float* __restrict__ gate,
    const float* __restrict__ bng, const float* __restrict__ bnb)
{
    const float rs = rsqrtf(1.f + 1e-5f);
    int idx4 = blockIdx.x * 256 + threadIdx.x;
    if (idx4 >= 1638400) return;
    int nc = idx4 / 400;          // 1600/4 float4 per channel
    int c = nc & 63;
    float4 val = ((const float4*)out)[idx4];
    float m = (1.f + gate[nc]) * (bng[c] * rs);
    float b = bnb[c];
    val.x = fmaxf(val.x * m + b, 0.f);
    val.y = fmaxf(val.y * m + b, 0.f);
    val.z = fmaxf(val.z * m + b, 0.f);
    val.w = fmaxf(val.w * m + b, 0.f);
    ((float4*)out)[idx4] = val;
}

extern "C" void kernel_launch(void* const* d_in, const int* in_sizes, int n_in,
                              void* d_out, int out_size, void* d_ws, size_t ws_size,
                              hipStream_t stream) {
    const float* x     = (const float*)d_in[0];
    const float* pe    = (const float*)d_in[1];
    const float* dbg   = (const float*)d_in[2];
    const float* dbb   = (const float*)d_in[3];
    const float* qkvw  = (const float*)d_in[4];
    const float* qkvb  = (const float*)d_in[5];
    const float* attnw = (const float*)d_in[6];
    const float* attnb = (const float*)d_in[7];
    const float* tcnw  = (const float*)d_in[8];
    const float* tcnb  = (const float*)d_in[9];
    const float* tcng  = (const float*)d_in[10];
    const float* tcnbb = (const float*)d_in[11];
    const float* fc1w  = (const float*)d_in[12];
    const float* fc1b  = (const float*)d_in[13];
    const float* fc2w  = (const float*)d_in[14];
    const float* fc2b  = (const float*)d_in[15];
    const float* bng   = (const float*)d_in[16];
    const float* bnb   = (const float*)d_in[17];

    float* out   = (float*)d_out;
    float* ao_ws = (float*)d_ws;                 // 64*16*1600 = 1,638,400 floats
    float* se    = ao_ws + 1638400;              // 4096 floats
    float* gate  = se + 4096;                    // 4096 floats

    hipMemsetAsync(se, 0, 4096 * sizeof(float), stream);
    attn_kernel<<<dim3(1600), dim3(256), 0, stream>>>(x, pe, dbg, dbb, qkvw, qkvb, attnw, attnb, ao_ws);
    tcn_kernel<<<dim3(9, 64), dim3(256), 0, stream>>>(x, tcnw, tcnb, tcng, tcnbb, ao_ws, out, se);
    gate_kernel<<<dim3(64), dim3(64), 0, stream>>>(se, fc1w, fc1b, fc2w, fc2b, gate);
    final_kernel<<<dim3(6400), dim3(256), 0, stream>>>(out, gate, bng, bnb);
}

// Round 2
// 334.829 us; speedup vs baseline: 1.3568x; 1.3568x over previous
//
#include <hip/hip_runtime.h>
#include <math.h>

#define TV_ 1600

__device__ __forceinline__ float tanh_fast(float x) {
    float u = fminf(10.f, fmaxf(-10.f, x));
    float e = __expf(2.f * u);
    return 1.f - 2.f / (e + 1.f);
}

// ---------------------------------------------------------------------------
// K1: per (n,v) block. Phases:
//  1. stage xn=bn(x), yb=x+pe, rawx(c>=48) in LDS
//  2. qkv GEMM, register-tiled (f:3rows x4t, p:2rows x4t per thread)
//  2b. write transposed [t][ch] arrays (stride 18)
//  3. mu; per-head weights+ao with float2 register fragments, shfl-reduce
//  4. attn_w projection + residual + out write (ch 48..63) + se atomics
// LDS: 9216 floats = 36 KB -> 4 blocks/CU
// ---------------------------------------------------------------------------
__global__ __launch_bounds__(256, 4) void attn_kernel(
    const float* __restrict__ x, const float* __restrict__ pe,
    const float* __restrict__ dbg, const float* __restrict__ dbb,
    const float* __restrict__ qkv_w, const float* __restrict__ qkv_b,
    const float* __restrict__ attn_w, const float* __restrict__ attn_b,
    float* __restrict__ out, float* __restrict__ se)
{
    __shared__ float sm[9216];
    const int b = blockIdx.x;
    const int l = b >> 3;
    const int n = (b & 7) * 8 + l / 25;   // XCD swizzle: same-n blocks share an XCD
    const int v = l % 25;
    const int tid = threadIdx.x;
    const float rs = rsqrtf(1.f + 1e-5f);

    // phase 1: staging
    for (int k = 0; k < 16; ++k) {
        int i = tid + k * 256;
        int c = i >> 6, t = i & 63;
        float xv = x[((n * 64 + c) * 64 + t) * 25 + v];
        sm[i] = xv * (dbg[c * 25 + v] * rs) + dbb[c * 25 + v];
        sm[4096 + i] = xv + pe[(c * 64 + t) * 25 + v];
        if (c >= 48) sm[8192 + (c - 48) * 64 + t] = xv;
    }
    __syncthreads();

    // phase 2: qkv. g = tid>>4 (16 row-groups), m = tid&15 (t-range 4m..4m+3)
    const int m = tid & 15, g = tid >> 4;
    float accf[3][4] = {{0}}, accp[2][4] = {{0}};
    int rf[3], wrf[3];
    const int rp0 = 2 * g, rp1 = 2 * g + 1;
    #pragma unroll
    for (int k = 0; k < 3; ++k) { int r = 3 * g + k; rf[k] = r; wrf[k] = (r < 32) ? r : r + 16; }

    for (int c0 = 0; c0 < 64; c0 += 4) {
        float wfl[12], wpl[8];
        *(float4*)&wfl[0] = *(const float4*)&qkv_w[wrf[0] * 64 + c0];
        *(float4*)&wfl[4] = *(const float4*)&qkv_w[wrf[1] * 64 + c0];
        *(float4*)&wfl[8] = *(const float4*)&qkv_w[wrf[2] * 64 + c0];
        *(float4*)&wpl[0] = *(const float4*)&qkv_w[rp0 * 64 + c0];
        *(float4*)&wpl[4] = *(const float4*)&qkv_w[rp1 * 64 + c0];
        #pragma unroll
        for (int cc = 0; cc < 4; ++cc) {
            float4 xf = *(const float4*)&sm[(c0 + cc) * 64 + 4 * m];
            float4 yp = *(const float4*)&sm[4096 + (c0 + cc) * 64 + 4 * m];
            #pragma unroll
            for (int k = 0; k < 3; ++k) {
                float w = wfl[k * 4 + cc];
                accf[k][0] += w * xf.x; accf[k][1] += w * xf.y;
                accf[k][2] += w * xf.z; accf[k][3] += w * xf.w;
            }
            #pragma unroll
            for (int k = 0; k < 2; ++k) {
                float w = wpl[k * 4 + cc];
                accp[k][0] += w * yp.x; accp[k][1] += w * yp.y;
                accp[k][2] += w * yp.z; accp[k][3] += w * yp.w;
            }
        }
    }
    float bf[3] = {qkv_b[wrf[0]], qkv_b[wrf[1]], qkv_b[wrf[2]]};
    float bp[2] = {qkv_b[rp0], qkv_b[rp1]};
    __syncthreads();   // all xn/yb reads done; region reused below

    // phase 2b: transposed stores. layout (floats): fqT@0 fkT@1152 fvT@2304
    // pqT@3456 pkT@4608 (each [64 t][18]), mu@5760, ao2@5776 ([64][20])
    const float RS2 = 0.70710678118654752f;
    #pragma unroll
    for (int k = 0; k < 3; ++k) {
        int r = rf[k];
        int base = (r < 16) ? 0 : (r < 32) ? 1152 : 2304;
        int ch = (r < 16) ? r : (r < 32) ? r - 16 : r - 32;
        float sc = (r < 16) ? RS2 : 1.f;
        #pragma unroll
        for (int j = 0; j < 4; ++j)
            sm[base + (4 * m + j) * 18 + ch] = (accf[k][j] + bf[k]) * sc;
    }
    #pragma unroll
    for (int k = 0; k < 2; ++k) {
        int r = (k == 0) ? rp0 : rp1;
        int base = (r < 16) ? 3456 : 4608;
        int ch = (r < 16) ? r : r - 16;
        float sc = (r < 16) ? RS2 : 1.f;
        #pragma unroll
        for (int j = 0; j < 4; ++j)
            sm[base + (4 * m + j) * 18 + ch] = (accp[k][j] + bp[k]) * sc;
    }
    __syncthreads();

    // mu over t for each of 16 fq channels
    if (tid < 16) {
        float s = 0.f;
        for (int t = 0; t < 64; ++t) s += sm[t * 18 + tid];
        sm[5760 + tid] = s * (1.f / 64.f);
    }
    __syncthreads();

    // phase 3: per-head. thread tile: 2 s x 8 t. m3 = tid>>3 (s), g3 = tid&7 (t)
    const int g3 = tid & 7, m3 = tid >> 3;
    for (int h = 0; h < 8; ++h) {
        float mux = sm[5760 + 2 * h], muy = sm[5760 + 2 * h + 1];
        float2 fk2[8], pk2[8], fv2[8];
        float un[8];
        #pragma unroll
        for (int jt = 0; jt < 8; ++jt) {
            int t = 8 * g3 + jt;
            fk2[jt] = *(const float2*)&sm[1152 + t * 18 + 2 * h];
            pk2[jt] = *(const float2*)&sm[4608 + t * 18 + 2 * h];
            fv2[jt] = *(const float2*)&sm[2304 + t * 18 + 2 * h];
            un[jt] = mux * fk2[jt].x + muy * fk2[jt].y;
        }
        float ao[2][2] = {{0.f, 0.f}, {0.f, 0.f}};
        #pragma unroll
        for (int js = 0; js < 2; ++js) {
            int s = 2 * m3 + js;
            float2 fq2 = *(const float2*)&sm[s * 18 + 2 * h];
            float2 pq2 = *(const float2*)&sm[3456 + s * 18 + 2 * h];
            float fcx = fq2.x - mux, fcy = fq2.y - muy;
            #pragma unroll
            for (int jt = 0; jt < 8; ++jt) {
                float lp = pq2.x * pk2[jt].x + pq2.y * pk2[jt].y;
                float pw = fcx * fk2[jt].x + fcy * fk2[jt].y;
                float w = tanh_fast(pw + lp) + tanh_fast(un[jt] + lp);
                ao[js][0] += w * fv2[jt].x;
                ao[js][1] += w * fv2[jt].y;
            }
        }
        // reduce over the 8 t-groups (low 3 lane bits)
        #pragma unroll
        for (int off = 1; off <= 4; off <<= 1) {
            ao[0][0] += __shfl_xor(ao[0][0], off);
            ao[0][1] += __shfl_xor(ao[0][1], off);
            ao[1][0] += __shfl_xor(ao[1][0], off);
            ao[1][1] += __shfl_xor(ao[1][1], off);
        }
        if (g3 == 0) {
            sm[5776 + (2 * m3) * 20 + 2 * h]         = ao[0][0];
            sm[5776 + (2 * m3) * 20 + 2 * h + 1]     = ao[0][1];
            sm[5776 + (2 * m3 + 1) * 20 + 2 * h]     = ao[1][0];
            sm[5776 + (2 * m3 + 1) * 20 + 2 * h + 1] = ao[1][1];
        }
    }
    __syncthreads();

    // phase 4: attn_w projection + rawx residual + out + se
    const int t = tid & 63, oq = tid >> 6;   // oq = wave id -> attn_w rows uniform
    float aorow[16];
    #pragma unroll
    for (int i = 0; i < 4; ++i)
        *(float4*)&aorow[i * 4] = *(const float4*)&sm[5776 + t * 20 + i * 4];
    #pragma unroll
    for (int j = 0; j < 4; ++j) {
        int o = oq * 4 + j;
        float acc = attn_b[o];
        #pragma unroll
        for (int ch = 0; ch < 16; ++ch) acc += attn_w[o * 16 + ch] * aorow[ch];
        float res = acc + sm[8192 + o * 64 + t];
        out[((n * 64 + 48 + o) * 64 + t) * 25 + v] = res;
        float ssum = res;
        #pragma unroll
        for (int off = 32; off >= 1; off >>= 1) ssum += __shfl_down(ssum, off, 64);
        if ((tid & 63) == 0) atomicAdd(&se[n * 64 + 48 + o], ssum);
    }
}

// ---------------------------------------------------------------------------
// K2: tcn conv, t-blocked. block = (n, ocg of 6 oc); thread = (v, 8 consec t).
// Weights are wave-uniform -> scalar loads. 432 FMA per 16 x-loads per ci.
// ---------------------------------------------------------------------------
__global__ __launch_bounds__(256, 2) void tcn_kernel(
    const float* __restrict__ x, const float* __restrict__ tcn_w,
    const float* __restrict__ tcn_b, const float* __restrict__ tg,
    const float* __restrict__ tb, float* __restrict__ out, float* __restrict__ se)
{
    const int b = blockIdx.x;
    const int n = (b & 7) * 8 + ((b >> 3) & 7);  // XCD swizzle: same-n together
    const int ocg = b >> 6;                       // 0..7
    const int tid = threadIdx.x;
    const bool active = tid < 200;
    const int v = tid % 25, t0 = (tid / 25) * 8;
    const float rsbn = rsqrtf(1.f + 1e-5f);

    float acc[8][6] = {{0}};
    for (int ci = 0; ci < 64; ++ci) {
        const float* xp = x + (n * 64 + ci) * TV_;
        float xw[16];
        #pragma unroll
        for (int j = 0; j < 16; ++j) {
            int tt = t0 - 4 + j;
            xw[j] = (active && tt >= 0 && tt < 64) ? xp[tt * 25 + v] : 0.f;
        }
        #pragma unroll
        for (int kt = 0; kt < 9; ++kt) {
            float w6[6];
            #pragma unroll
            for (int j = 0; j < 6; ++j)
                w6[j] = tcn_w[((ocg * 6 + j) * 64 + ci) * 9 + kt];  // uniform -> s_load
            #pragma unroll
            for (int t = 0; t < 8; ++t) {
                #pragma unroll
                for (int j = 0; j < 6; ++j)
                    acc[t][j] += w6[j] * xw[t + kt];
            }
        }
    }

    float chsum[6] = {0};
    if (active) {
        #pragma unroll
        for (int j = 0; j < 6; ++j) {
            int oc = ocg * 6 + j;
            float a = tg[oc] * rsbn;
            float c = tcn_b[oc] * a + tb[oc];
            #pragma unroll
            for (int t = 0; t < 8; ++t) {
                int pos = (t0 + t) * 25 + v;
                float val = acc[t][j] * a + c + x[(n * 64 + oc) * TV_ + pos];
                out[(n * 64 + oc) * TV_ + pos] = val;
                chsum[j] += val;
            }
        }
    }
    __shared__ float redbuf[4];
    #pragma unroll
    for (int j = 0; j < 6; ++j) {
        float s = chsum[j];
        #pragma unroll
        for (int off = 32; off >= 1; off >>= 1) s += __shfl_down(s, off, 64);
        if ((tid & 63) == 0) redbuf[tid >> 6] = s;
        __syncthreads();
        if (tid == 0)
            atomicAdd(&se[n * 64 + ocg * 6 + j], redbuf[0] + redbuf[1] + redbuf[2] + redbuf[3]);
        __syncthreads();
    }
}

// ---------------------------------------------------------------------------
// K3: SE gate MLP per n
// ---------------------------------------------------------------------------
__global__ __launch_bounds__(64) void gate_kernel(
    const float* __restrict__ se,
    const float* __restrict__ fc1w, const float* __restrict__ fc1b,
    const float* __restrict__ fc2w, const float* __restrict__ fc2b,
    float* __restrict__ gate)
{
    const int n = blockIdx.x;
    const int tid = threadIdx.x;
    __shared__ float seL[64], hid[32];
    seL[tid] = se[n * 64 + tid] * (1.f / (float)TV_);
    __syncthreads();
    if (tid < 32) {
        float a = fc1b[tid];
        #pragma unroll
        for (int c = 0; c < 64; ++c) a += fc1w[tid * 64 + c] * seL[c];
        hid[tid] = fmaxf(a, 0.f);
    }
    __syncthreads();
    float gacc = fc2b[tid];
    #pragma unroll
    for (int j = 0; j < 32; ++j) gacc += fc2w[tid * 32 + j] * hid[j];
    gate[n * 64 + tid] = 1.f / (1.f + __expf(-gacc));
}

// ---------------------------------------------------------------------------
// K4: out = relu((result*(1+gate)) * bn_s + bn_b)
// ---------------------------------------------------------------------------
__global__ __launch_bounds__(256) void final_kernel(
    float* __restrict__ out, const float* __restrict__ gate,
    const float* __restrict__ bng, const float* __restrict__ bnb)
{
    const float rs = rsqrtf(1.f + 1e-5f);
    int idx4 = blockIdx.x * 256 + threadIdx.x;
    if (idx4 >= 1638400) return;
    int nc = idx4 / 400;
    int c = nc & 63;
    float4 val = ((const float4*)out)[idx4];
    float mm = (1.f + gate[nc]) * (bng[c] * rs);
    float bb = bnb[c];
    val.x = fmaxf(val.x * mm + bb, 0.f);
    val.y = fmaxf(val.y * mm + bb, 0.f);
    val.z = fmaxf(val.z * mm + bb, 0.f);
    val.w = fmaxf(val.w * mm + bb, 0.f);
    ((float4*)out)[idx4] = val;
}

extern "C" void kernel_launch(void* const* d_in, const int* in_sizes, int n_in,
                              void* d_out, int out_size, void* d_ws, size_t ws_size,
                              hipStream_t stream) {
    const float* x     = (const float*)d_in[0];
    const float* pe    = (const float*)d_in[1];
    const float* dbg   = (const float*)d_in[2];
    const float* dbb   = (const float*)d_in[3];
    const float* qkvw  = (const float*)d_in[4];
    const float* qkvb  = (const float*)d_in[5];
    const float* attnw = (const float*)d_in[6];
    const float* attnb = (const float*)d_in[7];
    const float* tcnw  = (const float*)d_in[8];
    const float* tcnb  = (const float*)d_in[9];
    const float* tcng  = (const float*)d_in[10];
    const float* tcnbb = (const float*)d_in[11];
    const float* fc1w  = (const float*)d_in[12];
    const float* fc1b  = (const float*)d_in[13];
    const float* fc2w  = (const float*)d_in[14];
    const float* fc2b  = (const float*)d_in[15];
    const float* bng   = (const float*)d_in[16];
    const float* bnb   = (const float*)d_in[17];

    float* out  = (float*)d_out;
    float* se   = (float*)d_ws;            // 4096 floats
    float* gate = se + 4096;               // 4096 floats

    hipMemsetAsync(se, 0, 4096 * sizeof(float), stream);
    attn_kernel<<<dim3(1600), dim3(256), 0, stream>>>(x, pe, dbg, dbb, qkvw, qkvb, attnw, attnb, out, se);
    tcn_kernel<<<dim3(512), dim3(256), 0, stream>>>(x, tcnw, tcnb, tcng, tcnbb, out, se);
    gate_kernel<<<dim3(64), dim3(64), 0, stream>>>(se, fc1w, fc1b, fc2w, fc2b, gate);
    final_kernel<<<dim3(6400), dim3(256), 0, stream>>>(out, gate, bng, bnb);
}

// Round 3
// 327.497 us; speedup vs baseline: 1.3872x; 1.0224x over previous
//
#include <hip/hip_runtime.h>
#include <math.h>

#define TV_ 1600
#define SCALE_K 2.885390081777927f   // 2*log2(e): folded into fk/pk so tanh uses exp2 directly

// tanh(z) where y = 2*log2(e)*z is the pre-scaled argument:
// tanh(z) = (e-1)/(e+1), e = exp2(y). Clamp |y|<=44 so e1*e... and inf*0 NaN paths never occur.
__device__ __forceinline__ float tanh_scaled(float y) {
    y = fminf(44.f, fmaxf(-44.f, y));
    float e = __builtin_amdgcn_exp2f(y);
    float r = __builtin_amdgcn_rcpf(e + 1.f);
    return __builtin_fmaf(e, r, -r);
}

// ---------------------------------------------------------------------------
// K1: per (n,v) block. LDS 32 KB -> 5 blocks/CU.
//  planes after qkv: [16 rows][68] each (stride 68: phase-3 reads step 8*68
//  mod 32 = 0? no: reads step over g3 are +8 floats within a row -> 2-way free;
//  float4 stores aligned since 68 % 4 == 0).
// ---------------------------------------------------------------------------
__global__ __launch_bounds__(256, 5) void attn_kernel(
    const float* __restrict__ x, const float* __restrict__ pe,
    const float* __restrict__ dbg, const float* __restrict__ dbb,
    const float* __restrict__ qkv_w, const float* __restrict__ qkv_b,
    const float* __restrict__ attn_w, const float* __restrict__ attn_b,
    float* __restrict__ out, float* __restrict__ se)
{
    __shared__ float sm[8192];
    const int FQ = 0, FK = 1088, FV = 2176, PQ = 3264, PK = 4352, MU = 5440, AO = 5504;

    const int b = blockIdx.x;
    const int l = b >> 3;
    const int n = (b & 7) * 8 + l / 25;   // same-n blocks share an XCD
    const int v = l % 25;
    const int tid = threadIdx.x;
    const float rs = rsqrtf(1.f + 1e-5f);
    const float RS2 = 0.70710678118654752f;  // DKH^-0.5

    // phase 1: stage xn = bn(x) @0, yb = x+pe @4096
    for (int k = 0; k < 16; ++k) {
        int i = tid + k * 256;
        int c = i >> 6, t = i & 63;
        float xv = x[((n * 64 + c) * 64 + t) * 25 + v];
        sm[i] = xv * (dbg[c * 25 + v] * rs) + dbb[c * 25 + v];
        sm[4096 + i] = xv + pe[(c * 64 + t) * 25 + v];
    }
    __syncthreads();

    // phase 2: qkv GEMM. g = tid>>4 (row group), m = tid&15 (t = 4m..4m+3)
    const int m = tid & 15, g = tid >> 4;
    float accf[3][4] = {{0}}, accp[2][4] = {{0}};
    int rf[3], wrf[3];
    const int rp0 = 2 * g, rp1 = 2 * g + 1;
    #pragma unroll
    for (int k = 0; k < 3; ++k) { int r = 3 * g + k; rf[k] = r; wrf[k] = (r < 32) ? r : r + 16; }

    for (int c0 = 0; c0 < 64; c0 += 4) {
        float wfl[12], wpl[8];
        *(float4*)&wfl[0] = *(const float4*)&qkv_w[wrf[0] * 64 + c0];
        *(float4*)&wfl[4] = *(const float4*)&qkv_w[wrf[1] * 64 + c0];
        *(float4*)&wfl[8] = *(const float4*)&qkv_w[wrf[2] * 64 + c0];
        *(float4*)&wpl[0] = *(const float4*)&qkv_w[rp0 * 64 + c0];
        *(float4*)&wpl[4] = *(const float4*)&qkv_w[rp1 * 64 + c0];
        #pragma unroll
        for (int cc = 0; cc < 4; ++cc) {
            float4 xf = *(const float4*)&sm[(c0 + cc) * 64 + 4 * m];
            float4 yp = *(const float4*)&sm[4096 + (c0 + cc) * 64 + 4 * m];
            #pragma unroll
            for (int k = 0; k < 3; ++k) {
                float w = wfl[k * 4 + cc];
                accf[k][0] += w * xf.x; accf[k][1] += w * xf.y;
                accf[k][2] += w * xf.z; accf[k][3] += w * xf.w;
            }
            #pragma unroll
            for (int k = 0; k < 2; ++k) {
                float w = wpl[k * 4 + cc];
                accp[k][0] += w * yp.x; accp[k][1] += w * yp.y;
                accp[k][2] += w * yp.z; accp[k][3] += w * yp.w;
            }
        }
    }
    float bf[3] = {qkv_b[wrf[0]], qkv_b[wrf[1]], qkv_b[wrf[2]]};
    float bp[2] = {qkv_b[rp0], qkv_b[rp1]};
    __syncthreads();

    // phase 2b: aligned float4 stores into [row][68] planes.
    // fq,pq scaled by RS2; fk,pk scaled by SCALE_K (exp2 trick); fv unscaled.
    #pragma unroll
    for (int k = 0; k < 3; ++k) {
        int r = rf[k];
        int base = (r < 16) ? (FQ + r * 68) : (r < 32) ? (FK + (r - 16) * 68) : (FV + (r - 32) * 68);
        float sc = (r < 16) ? RS2 : (r < 32) ? SCALE_K : 1.f;
        float4 val = make_float4((accf[k][0] + bf[k]) * sc, (accf[k][1] + bf[k]) * sc,
                                 (accf[k][2] + bf[k]) * sc, (accf[k][3] + bf[k]) * sc);
        *(float4*)&sm[base + 4 * m] = val;
    }
    #pragma unroll
    for (int k = 0; k < 2; ++k) {
        int r = (k == 0) ? rp0 : rp1;
        int base = (r < 16) ? (PQ + r * 68) : (PK + (r - 16) * 68);
        float sc = (r < 16) ? RS2 : SCALE_K;
        float4 val = make_float4((accp[k][0] + bp[k]) * sc, (accp[k][1] + bp[k]) * sc,
                                 (accp[k][2] + bp[k]) * sc, (accp[k][3] + bp[k]) * sc);
        *(float4*)&sm[base + 4 * m] = val;
    }
    __syncthreads();

    // mu over t for the 16 fq channels (2-level: 64 threads do 16-t partials)
    if (tid < 64) {
        int ch = tid & 15, q = tid >> 4;
        float s = 0.f;
        #pragma unroll
        for (int t = 0; t < 16; ++t) s += sm[FQ + ch * 68 + q * 16 + t];
        sm[MU + q * 16 + ch] = s;
    }
    __syncthreads();
    if (tid < 16) {
        float mval = (sm[MU + tid] + sm[MU + 16 + tid] + sm[MU + 32 + tid] + sm[MU + 48 + tid]) * (1.f / 64.f);
        sm[MU + tid] = mval;
    }
    __syncthreads();

    // phase 3: per head; thread tile 2 s x 8 t. g3 = tid&7 (t octet), m3 = tid>>3 (s pair)
    const int g3 = tid & 7, m3 = tid >> 3;
    for (int h = 0; h < 8; ++h) {
        const int row0 = 2 * h * 68, row1 = row0 + 68;
        float mux = sm[MU + 2 * h], muy = sm[MU + 2 * h + 1];
        float fk0[8], fk1[8], pk0[8], pk1[8], fv0[8], fv1[8], un[8];
        #pragma unroll
        for (int jt = 0; jt < 8; ++jt) {
            int t = 8 * g3 + jt;
            fk0[jt] = sm[FK + row0 + t]; fk1[jt] = sm[FK + row1 + t];
            pk0[jt] = sm[PK + row0 + t]; pk1[jt] = sm[PK + row1 + t];
            fv0[jt] = sm[FV + row0 + t]; fv1[jt] = sm[FV + row1 + t];
            un[jt] = mux * fk0[jt] + muy * fk1[jt];
        }
        float ao[2][2] = {{0.f, 0.f}, {0.f, 0.f}};
        #pragma unroll
        for (int js = 0; js < 2; ++js) {
            int s = 2 * m3 + js;
            float fq0 = sm[FQ + row0 + s] - mux, fq1 = sm[FQ + row1 + s] - muy;
            float pq0 = sm[PQ + row0 + s], pq1 = sm[PQ + row1 + s];
            #pragma unroll
            for (int jt = 0; jt < 8; ++jt) {
                float lp = pq0 * pk0[jt] + pq1 * pk1[jt];
                float a1 = fq0 * fk0[jt] + fq1 * fk1[jt] + lp;
                float a2 = un[jt] + lp;
                float w = tanh_scaled(a1) + tanh_scaled(a2);
                ao[js][0] += w * fv0[jt];
                ao[js][1] += w * fv1[jt];
            }
        }
        #pragma unroll
        for (int off = 1; off <= 4; off <<= 1) {
            ao[0][0] += __shfl_xor(ao[0][0], off);
            ao[0][1] += __shfl_xor(ao[0][1], off);
            ao[1][0] += __shfl_xor(ao[1][0], off);
            ao[1][1] += __shfl_xor(ao[1][1], off);
        }
        if (g3 == 0) {
            sm[AO + (2 * m3) * 20 + 2 * h]         = ao[0][0];
            sm[AO + (2 * m3) * 20 + 2 * h + 1]     = ao[0][1];
            sm[AO + (2 * m3 + 1) * 20 + 2 * h]     = ao[1][0];
            sm[AO + (2 * m3 + 1) * 20 + 2 * h + 1] = ao[1][1];
        }
    }
    __syncthreads();

    // phase 4: attn_w projection + residual (global x) + out + se
    const int t = tid & 63, oq = tid >> 6;
    float aorow[16];
    #pragma unroll
    for (int i = 0; i < 4; ++i)
        *(float4*)&aorow[i * 4] = *(const float4*)&sm[AO + t * 20 + i * 4];
    #pragma unroll
    for (int j = 0; j < 4; ++j) {
        int o = oq * 4 + j;
        float acc = attn_b[o];
        #pragma unroll
        for (int ch = 0; ch < 16; ++ch) acc += attn_w[o * 16 + ch] * aorow[ch];
        float res = acc + x[((n * 64 + 48 + o) * 64 + t) * 25 + v];
        out[((n * 64 + 48 + o) * 64 + t) * 25 + v] = res;
        float ssum = res;
        #pragma unroll
        for (int off = 32; off >= 1; off >>= 1) ssum += __shfl_down(ssum, off, 64);
        if ((tid & 63) == 0) atomicAdd(&se[n * 64 + 48 + o], ssum);
    }
}

// ---------------------------------------------------------------------------
// K2: tcn conv. grid = 64 n x 8 ocg x 2 t-halves = 1024 -> 4 blocks/CU.
// Thread = (v, 4 consec t); next-ci x-window software-prefetched.
// Weights wave-uniform -> SGPR s_loads.
// ---------------------------------------------------------------------------
__global__ __launch_bounds__(256, 4) void tcn_kernel(
    const float* __restrict__ x, const float* __restrict__ tcn_w,
    const float* __restrict__ tcn_b, const float* __restrict__ tg,
    const float* __restrict__ tb, float* __restrict__ out, float* __restrict__ se)
{
    const int b = blockIdx.x;
    const int n = (b & 7) * 8 + ((b >> 3) & 7);  // same-n blocks share an XCD
    const int rest = b >> 6;
    const int ocg = rest & 7, th = rest >> 3;
    const int tid = threadIdx.x;
    const bool active = tid < 200;
    const int v = tid % 25, t0 = th * 32 + (tid / 25) * 4;
    const float rsbn = rsqrtf(1.f + 1e-5f);

    float acc[4][6] = {{0}};
    float xwN[12];
    {
        const float* xp = x + (n * 64 + 0) * TV_;
        #pragma unroll
        for (int j = 0; j < 12; ++j) {
            int tt = t0 - 4 + j;
            xwN[j] = (active && tt >= 0 && tt < 64) ? xp[tt * 25 + v] : 0.f;
        }
    }
    for (int ci = 0; ci < 64; ++ci) {
        float xw[12];
        #pragma unroll
        for (int j = 0; j < 12; ++j) xw[j] = xwN[j];
        if (ci < 63) {
            const float* xp = x + (n * 64 + ci + 1) * TV_;
            #pragma unroll
            for (int j = 0; j < 12; ++j) {
                int tt = t0 - 4 + j;
                xwN[j] = (active && tt >= 0 && tt < 64) ? xp[tt * 25 + v] : 0.f;
            }
        }
        float wj[54];
        #pragma unroll
        for (int j6 = 0; j6 < 6; ++j6)
            #pragma unroll
            for (int kt = 0; kt < 9; ++kt)
                wj[j6 * 9 + kt] = tcn_w[((ocg * 6 + j6) * 64 + ci) * 9 + kt];  // uniform
        #pragma unroll
        for (int kt = 0; kt < 9; ++kt)
            #pragma unroll
            for (int t = 0; t < 4; ++t)
                #pragma unroll
                for (int j6 = 0; j6 < 6; ++j6)
                    acc[t][j6] += wj[j6 * 9 + kt] * xw[t + kt];
    }

    float chsum[6] = {0};
    if (active) {
        #pragma unroll
        for (int j6 = 0; j6 < 6; ++j6) {
            int oc = ocg * 6 + j6;
            float a = tg[oc] * rsbn;
            float c = tcn_b[oc] * a + tb[oc];
            #pragma unroll
            for (int t = 0; t < 4; ++t) {
                int pos = (t0 + t) * 25 + v;
                float val = acc[t][j6] * a + c + x[(n * 64 + oc) * TV_ + pos];
                out[(n * 64 + oc) * TV_ + pos] = val;
                chsum[j6] += val;
            }
        }
    }
    __shared__ float redbuf[4];
    #pragma unroll
    for (int j6 = 0; j6 < 6; ++j6) {
        float s = chsum[j6];
        #pragma unroll
        for (int off = 32; off >= 1; off >>= 1) s += __shfl_down(s, off, 64);
        if ((tid & 63) == 0) redbuf[tid >> 6] = s;
        __syncthreads();
        if (tid == 0)
            atomicAdd(&se[n * 64 + ocg * 6 + j6], redbuf[0] + redbuf[1] + redbuf[2] + redbuf[3]);
        __syncthreads();
    }
}

// ---------------------------------------------------------------------------
// K3: SE gate MLP per n
// ---------------------------------------------------------------------------
__global__ __launch_bounds__(64) void gate_kernel(
    const float* __restrict__ se,
    const float* __restrict__ fc1w, const float* __restrict__ fc1b,
    const float* __restrict__ fc2w, const float* __restrict__ fc2b,
    float* __restrict__ gate)
{
    const int n = blockIdx.x;
    const int tid = threadIdx.x;
    __shared__ float seL[64], hid[32];
    seL[tid] = se[n * 64 + tid] * (1.f / (float)TV_);
    __syncthreads();
    if (tid < 32) {
        float a = fc1b[tid];
        #pragma unroll
        for (int c = 0; c < 64; ++c) a += fc1w[tid * 64 + c] * seL[c];
        hid[tid] = fmaxf(a, 0.f);
    }
    __syncthreads();
    float gacc = fc2b[tid];
    #pragma unroll
    for (int j = 0; j < 32; ++j) gacc += fc2w[tid * 32 + j] * hid[j];
    gate[n * 64 + tid] = 1.f / (1.f + __expf(-gacc));
}

// ---------------------------------------------------------------------------
// K4: out = relu((result*(1+gate)) * bn_s + bn_b)
// ---------------------------------------------------------------------------
__global__ __launch_bounds__(256) void final_kernel(
    float* __restrict__ out, const float* __restrict__ gate,
    const float* __restrict__ bng, const float* __restrict__ bnb)
{
    const float rs = rsqrtf(1.f + 1e-5f);
    int idx4 = blockIdx.x * 256 + threadIdx.x;
    if (idx4 >= 1638400) return;
    int nc = idx4 / 400;
    int c = nc & 63;
    float4 val = ((const float4*)out)[idx4];
    float mm = (1.f + gate[nc]) * (bng[c] * rs);
    float bb = bnb[c];
    val.x = fmaxf(val.x * mm + bb, 0.f);
    val.y = fmaxf(val.y * mm + bb, 0.f);
    val.z = fmaxf(val.z * mm + bb, 0.f);
    val.w = fmaxf(val.w * mm + bb, 0.f);
    ((float4*)out)[idx4] = val;
}

extern "C" void kernel_launch(void* const* d_in, const int* in_sizes, int n_in,
                              void* d_out, int out_size, void* d_ws, size_t ws_size,
                              hipStream_t stream) {
    const float* x     = (const float*)d_in[0];
    const float* pe    = (const float*)d_in[1];
    const float* dbg   = (const float*)d_in[2];
    const float* dbb   = (const float*)d_in[3];
    const float* qkvw  = (const float*)d_in[4];
    const float* qkvb  = (const float*)d_in[5];
    const float* attnw = (const float*)d_in[6];
    const float* attnb = (const float*)d_in[7];
    const float* tcnw  = (const float*)d_in[8];
    const float* tcnb  = (const float*)d_in[9];
    const float* tcng  = (const float*)d_in[10];
    const float* tcnbb = (const float*)d_in[11];
    const float* fc1w  = (const float*)d_in[12];
    const float* fc1b  = (const float*)d_in[13];
    const float* fc2w  = (const float*)d_in[14];
    const float* fc2b  = (const float*)d_in[15];
    const float* bng   = (const float*)d_in[16];
    const float* bnb   = (const float*)d_in[17];

    float* out  = (float*)d_out;
    float* se   = (float*)d_ws;            // 4096 floats
    float* gate = se + 4096;               // 4096 floats

    hipMemsetAsync(se, 0, 4096 * sizeof(float), stream);
    attn_kernel<<<dim3(1600), dim3(256), 0, stream>>>(x, pe, dbg, dbb, qkvw, qkvb, attnw, attnb, out, se);
    tcn_kernel<<<dim3(1024), dim3(256), 0, stream>>>(x, tcnw, tcnb, tcng, tcnbb, out, se);
    gate_kernel<<<dim3(64), dim3(64), 0, stream>>>(se, fc1w, fc1b, fc2w, fc2b, gate);
    final_kernel<<<dim3(6400), dim3(256), 0, stream>>>(out, gate, bng, bnb);
}